// Round 9
// baseline (181.479 us; speedup 1.0000x reference)
//
#include <hip/hip_runtime.h>
#include <math.h>

// Problem constants
#define K_CODES 1024
#define C_DIM   128
#define HW      4096          // 64*64
#define CHW     (C_DIM*HW)    // per-batch stride in x
#define N_POS   65536         // 16*64*64
#define Q_ELEMS 8388608       // 16*128*64*64

// ws layout (byte offsets). Total = 270336 B, proven safe rounds 1-8.
#define WS_S    0             // float: sum of sqrt(d2min)
#define WS_CNT  4             // uint: completed-block counter (last-block fin)
#define WS_C2   256           // float[1024]: ||c_k||^2
#define WS_CBBF 8192          // bf16 codebook, 256 KB; row k at k*256B,
                              // granule-col j holds channels of granule
                              // (j ^ (k&7)) -> linear gll staging +
                              // conflict-free swizzled ds_read_b128 A-frags.

typedef __attribute__((ext_vector_type(8))) short short8;   // 8 bf16 (4 VGPRs)
typedef __attribute__((ext_vector_type(4))) float f32x4;    // MFMA acc

__device__ __forceinline__ unsigned short f2bf(float f) {   // fp32 -> bf16 RNE
    unsigned u = __float_as_uint(f);
    u += 0x7FFFu + ((u >> 16) & 1u);
    return (unsigned short)(u >> 16);
}

// async global->LDS, 16B per lane; LDS dst = wave-uniform base + lane*16
__device__ __forceinline__ void gll16(const void* g, void* l) {
    __builtin_amdgcn_global_load_lds(
        (const __attribute__((address_space(1))) void*)g,
        (__attribute__((address_space(3))) void*)l, 16, 0, 0);
}

// ---------------------------------------------------------------------------
// Kernel 1: prep (unchanged from R8). Block k (64 lanes): row norm, bf16
// conversion into the column-swizzled layout in ws, S/cnt zeroing.
// ---------------------------------------------------------------------------
__global__ void prep_kernel(const float* __restrict__ cb, float* __restrict__ ws) {
    __shared__ __align__(16) unsigned short srow[128];
    unsigned short* cbbf = (unsigned short*)((char*)ws + WS_CBBF);
    int k = blockIdx.x;
    int l = threadIdx.x;                       // 64 lanes = 1 wave
    if (k == 0 && l == 0) {
        *(float*)((char*)ws + WS_S) = 0.f;
        *(unsigned*)((char*)ws + WS_CNT) = 0u;
    }
    float v1 = cb[k * C_DIM + l];
    float v2 = cb[k * C_DIM + 64 + l];
    int c1 = l, c2 = 64 + l;
    srow[(((c1 >> 3) ^ (k & 7)) << 3) | (c1 & 7)] = f2bf(v1);
    srow[(((c2 >> 3) ^ (k & 7)) << 3) | (c2 & 7)] = f2bf(v2);
    float ss = v1 * v1 + v2 * v2;
    #pragma unroll
    for (int off = 32; off > 0; off >>= 1) ss += __shfl_down(ss, off);
    if (l == 0) ((float*)((char*)ws + WS_C2))[k] = ss;
    __syncthreads();
    if (l < 16) ((uint4*)cbbf)[k * 16 + l] = ((const uint4*)srow)[l];
}

// ---------------------------------------------------------------------------
// Kernel 2: fully fused VQ. Main MFMA loop byte-identical to R6-R8 (absmax
// 0.0 three times). NEW tails (R9): all codebook-row traffic is now
// WAVE-COOPERATIVE (row uniform per instruction -> coalesced 512B reads)
// instead of per-lane random-row gathers (fan-out ~64 L1 transactions per
// instruction -- the R8 regression cause):
//  phase 3: x tile staged fp32 into xT (reuses cbuf LDS region); each wave
//           rescores 16 positions x 3 candidates with coalesced cb reads +
//           butterfly reduction; writes final idx to kbuf + loss atomic.
//  phase 4: chosen rows gathered coalesced into XOR-swizzled qT (same LDS
//           region), then scattered to out with lane=position (256B stores).
//  Last block (atomic counter + threadfence) writes the two loss scalars.
// ---------------------------------------------------------------------------
__global__ __launch_bounds__(256, 2) void vq_mfma(const float* __restrict__ x,
                                                  const float* __restrict__ cb,
                                                  float* __restrict__ ws,
                                                  float* __restrict__ out) {
    __shared__ __align__(16) char ubuf[64 * 132 * 4];  // 33792 B: cbuf / xT / qT
    __shared__ float mbuf[2][2][16][3];                // 768 B
    __shared__ int   kbuf3[64][3];                     // 768 B: top-3 per pos
    __shared__ float r2buf[64];                        // 256 B
    __shared__ int   kbuf[64];                         // 256 B: final idx

    const unsigned short* cbbf = (const unsigned short*)((const char*)ws + WS_CBBF);
    const float* c2w = (const float*)((const char*)ws + WS_C2);
    float*    Sw   = (float*)((char*)ws + WS_S);
    unsigned* cntw = (unsigned*)((char*)ws + WS_CNT);
    unsigned short* cbuf = (unsigned short*)ubuf;

    const int t  = threadIdx.x;
    const int w  = t >> 6;                      // wave 0..3
    const int kh = w & 1;                       // code half
    const int pg = w >> 1;                      // position group (32 pos)
    const int ln = t & 63;
    const int lp = ln & 15;                     // position lane (n index)
    const int q  = ln >> 4;                     // quad 0..3 (k sub-range)
    const int bid = blockIdx.x;
    const int b   = bid >> 6;                   // batch (64 blocks per image)
    const int s0  = (bid & 63) << 6;            // 64-position tile start

    // ---- x: bf16 B-frags (2 pos-tiles) + per-position norms ----
    short8 xf[2][4];
    float  r2v[2];
    {
        float ss[2] = {0.f, 0.f};
        #pragma unroll
        for (int pt = 0; pt < 2; ++pt) {
            const float* xgp = x + b * CHW + s0 + pg * 32 + pt * 16 + lp;
            #pragma unroll
            for (int cs = 0; cs < 4; ++cs) {
                union { short8 v; unsigned short u[8]; } fu;
                #pragma unroll
                for (int j = 0; j < 8; ++j) {
                    float vv = xgp[(32 * cs + 8 * q + j) * HW];
                    ss[pt] = fmaf(vv, vv, ss[pt]);
                    fu.u[j] = f2bf(vv);
                }
                xf[pt][cs] = fu.v;
            }
        }
        #pragma unroll
        for (int pt = 0; pt < 2; ++pt) {
            float s = ss[pt];
            s += __shfl_xor(s, 16);
            s += __shfl_xor(s, 32);
            r2v[pt] = -2.0f / fmaxf(sqrtf(s), 1e-12f);  // F.normalize eps
        }
    }

    const float FMAX = __uint_as_float(0x7F7FFFFFu);
    float m1[2] = {FMAX, FMAX}, m2[2] = {FMAX, FMAX}, m3[2] = {FMAX, FMAX};

    // staging bases: per-lane global addr, wave-uniform LDS base
    const char* gbase = (const char*)cbbf + (kh * 512) * 256 + (pg * 512 + ln) * 16;
    char* lbase = (char*)cbuf + (kh * 1024 + pg * 512) * 16;

    #pragma unroll
    for (int r = 0; r < 8; ++r)                  // stage chunk 0
        gll16(gbase + r * 1024, lbase + r * 1024);
    __syncthreads();

    for (int i = 0; i < 8; ++i) {
        const int k0 = kh * 512 + i * 64;

        f32x4 acc[4][2];
        #pragma unroll
        for (int ct = 0; ct < 4; ++ct)
            #pragma unroll
            for (int pt = 0; pt < 2; ++pt) acc[ct][pt] = 0;

        const unsigned short* cbp = cbuf + kh * 8192;
        #pragma unroll
        for (int cs = 0; cs < 4; ++cs) {
            short8 ah[4];
            #pragma unroll
            for (int ct = 0; ct < 4; ++ct) {     // A[m=16ct+lp][k=32cs+8q+j]
                int g = (16 * ct + lp) * 16 + ((4 * cs + q) ^ (lp & 7));
                ah[ct] = *(const short8*)(cbp + g * 8);
            }
            #pragma unroll
            for (int ct = 0; ct < 4; ++ct)
                #pragma unroll
                for (int pt = 0; pt < 2; ++pt)
                    acc[ct][pt] = __builtin_amdgcn_mfma_f32_16x16x32_bf16(
                        ah[ct], xf[pt][cs], acc[ct][pt], 0, 0, 0);
        }

        // ---- epilogue: 32 scores, ~5 VALU each (fmaf, and_or, 2 med3, min) --
        #pragma unroll
        for (int ct = 0; ct < 4; ++ct) {
            float4 c2vv = *(const float4*)(c2w + k0 + 16 * ct + 4 * q);
            float c2a[4] = {c2vv.x, c2vv.y, c2vv.z, c2vv.w};
            const int kb0 = k0 + 16 * ct + 4 * q;
            #pragma unroll
            for (int pt = 0; pt < 2; ++pt) {
                #pragma unroll
                for (int reg = 0; reg < 4; ++reg) {
                    float s = fmaf(r2v[pt], acc[ct][pt][reg], c2a[reg]);
                    unsigned pb = (__float_as_uint(s) & 0xFFFFFC00u) |
                                  (unsigned)(kb0 + reg);
                    float u  = __uint_as_float(pb);
                    float t3 = __builtin_amdgcn_fmed3f(m2[pt], m3[pt], u);
                    float t2 = __builtin_amdgcn_fmed3f(m1[pt], m2[pt], u);
                    m1[pt] = fminf(m1[pt], u); m2[pt] = t2; m3[pt] = t3;
                }
            }
        }

        if (i < 7) {
            __syncthreads();                     // all reads of buffer done
            #pragma unroll
            for (int r = 0; r < 8; ++r)
                gll16(gbase + (i + 1) * 16384 + r * 1024, lbase + r * 1024);
            __syncthreads();                     // loads landed (vmcnt drain)
        }
    }

    // ---- merge chains across the 4 quad-lanes (butterfly: all lanes get it) --
    #pragma unroll
    for (int d = 16; d <= 32; d <<= 1) {
        #pragma unroll
        for (int pt = 0; pt < 2; ++pt) {
            float o1 = __shfl_xor(m1[pt], d), o2 = __shfl_xor(m2[pt], d),
                  o3 = __shfl_xor(m3[pt], d);
            float u, t2, t3;
            u = o1; t3 = __builtin_amdgcn_fmed3f(m2[pt], m3[pt], u);
            t2 = __builtin_amdgcn_fmed3f(m1[pt], m2[pt], u);
            m1[pt] = fminf(m1[pt], u); m2[pt] = t2; m3[pt] = t3;
            u = o2; t3 = __builtin_amdgcn_fmed3f(m2[pt], m3[pt], u);
            t2 = __builtin_amdgcn_fmed3f(m1[pt], m2[pt], u);
            m1[pt] = fminf(m1[pt], u); m2[pt] = t2; m3[pt] = t3;
            u = o3; t3 = __builtin_amdgcn_fmed3f(m2[pt], m3[pt], u);
            t2 = __builtin_amdgcn_fmed3f(m1[pt], m2[pt], u);
            m1[pt] = fminf(m1[pt], u); m2[pt] = t2; m3[pt] = t3;
        }
    }

    if (kh == 1 && ln < 16) {
        #pragma unroll
        for (int pt = 0; pt < 2; ++pt) {
            mbuf[pg][pt][lp][0] = m1[pt];
            mbuf[pg][pt][lp][1] = m2[pt];
            mbuf[pg][pt][lp][2] = m3[pt];
        }
    }
    __syncthreads();

    // ---- kh=0 waves: merge halves, publish top-3 + r2 per position ----
    if (kh == 0 && ln < 16) {
        #pragma unroll
        for (int pt = 0; pt < 2; ++pt) {
            #pragma unroll
            for (int c = 0; c < 3; ++c) {
                float u  = mbuf[pg][pt][lp][c];
                float t3 = __builtin_amdgcn_fmed3f(m2[pt], m3[pt], u);
                float t2 = __builtin_amdgcn_fmed3f(m1[pt], m2[pt], u);
                m1[pt] = fminf(m1[pt], u); m2[pt] = t2; m3[pt] = t3;
            }
            int p = pg * 32 + pt * 16 + lp;
            kbuf3[p][0] = (int)(__float_as_uint(m1[pt]) & 1023u);
            kbuf3[p][1] = (int)(__float_as_uint(m2[pt]) & 1023u);
            kbuf3[p][2] = (int)(__float_as_uint(m3[pt]) & 1023u);
            r2buf[p] = r2v[pt];
        }
    }
    __syncthreads();                             // kbuf3/r2buf ready; cbuf free

    // ---- phase 3a: stage x tile fp32 into xT[64][132] (reuses cbuf region) --
    float* xT = (float*)ubuf;
    {
        const int p = pg * 32 + kh * 16 + lp;    // 4 waves cover 64 positions
        const float* xgp = x + b * CHW + s0 + p; // L1/L2-hot re-read
        #pragma unroll
        for (int cs = 0; cs < 4; ++cs) {
            float4 v0, v1;
            v0.x = xgp[(32 * cs + 8 * q + 0) * HW];
            v0.y = xgp[(32 * cs + 8 * q + 1) * HW];
            v0.z = xgp[(32 * cs + 8 * q + 2) * HW];
            v0.w = xgp[(32 * cs + 8 * q + 3) * HW];
            v1.x = xgp[(32 * cs + 8 * q + 4) * HW];
            v1.y = xgp[(32 * cs + 8 * q + 5) * HW];
            v1.z = xgp[(32 * cs + 8 * q + 6) * HW];
            v1.w = xgp[(32 * cs + 8 * q + 7) * HW];
            int wb = p * 132 + 32 * cs + 8 * q;
            *(float4*)&xT[wb]     = v0;
            *(float4*)&xT[wb + 4] = v1;
        }
    }
    __syncthreads();

    // ---- phase 3b: cooperative exact fp32 rescore. Wave w: positions
    // [16w,16w+16). Per candidate row: coalesced cb float2 + xT b64 +
    // 64-lane butterfly reduce (row uniform -> no gather fan-out).
    {
        float lloss = 0.f;
        for (int i = 0; i < 16; ++i) {
            const int p  = 16 * w + i;
            const int ka = kbuf3[p][0], kc1 = kbuf3[p][1], kc2 = kbuf3[p][2];
            const float r2p = r2buf[p];
            const float2 xv = *(const float2*)&xT[p * 132 + 2 * ln];
            float d[3];
            const int krow[3] = {ka, kc1, kc2};
            #pragma unroll
            for (int jj = 0; jj < 3; ++jj) {
                const float2 cv = *(const float2*)&cb[krow[jj] * C_DIM + 2 * ln];
                float pp = fmaf(xv.y, cv.y, xv.x * cv.x);
                #pragma unroll
                for (int dd = 1; dd <= 32; dd <<= 1) pp += __shfl_xor(pp, dd);
                d[jj] = pp;                       // all lanes hold full dot
            }
            float sb = fmaf(r2p, d[0], c2w[ka]); int kb = ka;
            float s2 = fmaf(r2p, d[1], c2w[kc1]);
            if (s2 < sb || (s2 == sb && kc1 < kb)) { sb = s2; kb = kc1; }
            float s3 = fmaf(r2p, d[2], c2w[kc2]);
            if (s3 < sb || (s3 == sb && kc2 < kb)) { sb = s3; kb = kc2; }
            if (ln == i) {                        // one lane owns position p
                kbuf[p] = kb;
                lloss = sqrtf(fmaxf(1.0f + sb, 0.f));  // z2==1 after normalize
            }
        }
        float ls = lloss;                         // lanes 16..63 contribute 0
        #pragma unroll
        for (int off = 32; off > 0; off >>= 1) ls += __shfl_down(ls, off);
        if (ln == 0) atomicAdd(Sw, ls);           // each position counted once
    }
    __syncthreads();                              // kbuf ready; xT reads done

    // ---- phase 4: cooperative q-scatter via XOR-swizzled qT (same region) --
    float* qT = (float*)ubuf;
    #pragma unroll 4
    for (int i = 0; i < 16; ++i) {
        const int p = 16 * w + i;
        const int row = kbuf[p];                  // wave-uniform
        const float2 cv = *(const float2*)&cb[row * C_DIM + 2 * ln];  // L1-hot
        const int g = ln ^ (p & 31);              // granule swizzle
        *(float2*)&qT[p * 132 + 2 * g] = cv;      // conflict-free b64 writes
    }
    __syncthreads();
    {
        float* o = out + b * CHW + s0 + ln;       // lane = position
        #pragma unroll 4
        for (int cc = 0; cc < 16; ++cc) {
            const int c2 = 16 * w + cc;           // wave w: channels [32w,32w+32)
            const int g = c2 ^ (ln & 31);
            const float2 v = *(const float2*)&qT[ln * 132 + 2 * g];
            o[(2 * c2) * HW]     = v.x;           // coalesced 256B stores
            o[(2 * c2 + 1) * HW] = v.y;
        }
    }

    // ---- last block writes the loss scalars (device-scope, worked in R8) ----
    if (t == 0) {
        __threadfence();
        unsigned c = atomicAdd(cntw, 1u);
        if (c == (unsigned)(gridDim.x - 1)) {
            float S = atomicAdd(Sw, 0.0f);
            float m = S / (float)N_POS;
            out[Q_ELEMS]     = 0.25f * m;
            out[Q_ELEMS + 1] = m;
        }
    }
}

extern "C" void kernel_launch(void* const* d_in, const int* in_sizes, int n_in,
                              void* d_out, int out_size, void* d_ws, size_t ws_size,
                              hipStream_t stream) {
    const float* x  = (const float*)d_in[0];   // [16,128,64,64]
    const float* cb = (const float*)d_in[1];   // [1024,128]
    float* out = (float*)d_out;
    float* ws  = (float*)d_ws;

    prep_kernel<<<K_CODES, 64, 0, stream>>>(cb, ws);
    vq_mfma    <<<N_POS / 64, 256, 0, stream>>>(x, cb, ws, out);
}

// Round 10
// 157.472 us; speedup vs baseline: 1.1525x; 1.1525x over previous
//
#include <hip/hip_runtime.h>
#include <math.h>

// Problem constants
#define K_CODES 1024
#define C_DIM   128
#define HW      4096          // 64*64
#define CHW     (C_DIM*HW)    // per-batch stride in x
#define N_POS   65536         // 16*64*64
#define Q_ELEMS 8388608       // 16*128*64*64

// ws layout (byte offsets). Total = 270336 B, proven safe rounds 1-9.
#define WS_S    0             // float: sum of sqrt(d2min)
#define WS_C2   256           // float[1024]: ||c_k||^2
#define WS_IDX  8192          // int[65536]: final argmin index per position

// d_out scratch (overwritten by write_q later; stream-ordered, proven in R7):
// bf16 codebook in A-FRAGMENT LANE ORDER: 16B granule g of code k (channels
// 8g..8g+7) lives at uint4 index  G = (k>>4)*256 + (g>>2)*64 + (g&3)*16 + (k&15)
// -> a wave's A-frag load for (tile T, cs) is uint4[T*256 + cs*64 + lane]:
//    perfectly coalesced 1KB global loads, no LDS staging, no barriers.

typedef __attribute__((ext_vector_type(8))) short short8;   // 8 bf16 (4 VGPRs)
typedef __attribute__((ext_vector_type(4))) float f32x4;    // MFMA acc

__device__ __forceinline__ unsigned short f2bf(float f) {   // fp32 -> bf16 RNE
    unsigned u = __float_as_uint(f);
    u += 0x7FFFu + ((u >> 16) & 1u);
    return (unsigned short)(u >> 16);
}

// ---------------------------------------------------------------------------
// Kernel 1: prep. Block k (64 lanes): row norm (same math as rounds 1-9),
// bf16 conversion into the A-frag-ordered layout in d_out, S zeroing.
// ---------------------------------------------------------------------------
__global__ void prep_kernel(const float* __restrict__ cb, float* __restrict__ ws,
                            unsigned short* __restrict__ cbbf) {
    __shared__ __align__(16) unsigned short srow[128];
    int k = blockIdx.x;
    int l = threadIdx.x;                       // 64 lanes = 1 wave
    if (k == 0 && l == 0) *(float*)((char*)ws + WS_S) = 0.f;
    float v1 = cb[k * C_DIM + l];
    float v2 = cb[k * C_DIM + 64 + l];
    srow[l]      = f2bf(v1);                   // plain channel order
    srow[64 + l] = f2bf(v2);
    float ss = v1 * v1 + v2 * v2;
    #pragma unroll
    for (int off = 32; off > 0; off >>= 1) ss += __shfl_down(ss, off);
    if (l == 0) ((float*)((char*)ws + WS_C2))[k] = ss;
    __syncthreads();
    if (l < 16) {                              // granule g = l
        int G = (k >> 4) * 256 + (l >> 2) * 64 + (l & 3) * 16 + (k & 15);
        ((uint4*)cbbf)[G] = ((const uint4*)srow)[l];
    }
}

// ---------------------------------------------------------------------------
// Kernel 2: VQ scorer. 1024 blocks x 256 thr. Block = 64 positions; wave w
// owns codes [256w, 256w+256) over ALL 64 positions (4 pos-tiles in regs).
// Main loop: 16 chunks of 16 codes; A-frags = 4 coalesced global dwordx4
// from the A-frag-ordered cbbf (L2-resident) -> NO LDS staging, NO barriers,
// compiler software-pipelines loads across chunks. Top-3 per position per
// wave via min+2x med3 (idx in low 10 mantissa bits). One barrier at the
// end: waves exchange chains via tiny LDS, wave w merges 12 candidates for
// positions [16w,16w+16), exact fp32 rescore (R7-proven math), idx + loss.
// 34KB LDS anchor caps occupancy at 4 blocks/CU so the allocator budgets
// ~128 VGPRs (R5/R9 showed small-LDS shapes trigger a 64-reg AGPR-spill
// squeeze that wrecks the main loop).
// ---------------------------------------------------------------------------
__global__ __launch_bounds__(256, 2) void vq_mfma(const float* __restrict__ x,
                                                  const float* __restrict__ cb,
                                                  const unsigned short* __restrict__ cbbf,
                                                  const float* __restrict__ ws,
                                                  int* __restrict__ idxw,
                                                  float* __restrict__ Sw) {
    __shared__ __align__(16) char smem[34816];       // occupancy anchor
    float (*mbuf)[4][16][3] = (float (*)[4][16][3])smem;  // [src w][pt][lp][c]

    const float* c2w = (const float*)((const char*)ws + WS_C2);

    const int t  = threadIdx.x;
    const int w  = t >> 6;                      // wave 0..3 = code quarter
    const int ln = t & 63;
    const int lp = ln & 15;                     // position lane (n index)
    const int q  = ln >> 4;                     // quad 0..3 (k sub-range)
    const int bid = blockIdx.x;
    const int b   = bid >> 6;                   // batch (64 blocks per image)
    const int s0  = (bid & 63) << 6;            // 64-position tile start

    // ---- x: bf16 B-frags (4 pos-tiles, 64 VGPRs) + per-tile norms ----
    short8 xf[4][4];
    float  r2v[4];
    {
        float ss[4] = {0.f, 0.f, 0.f, 0.f};
        #pragma unroll
        for (int pt = 0; pt < 4; ++pt) {
            const float* xgp = x + b * CHW + s0 + pt * 16 + lp;
            #pragma unroll
            for (int cs = 0; cs < 4; ++cs) {
                union { short8 v; unsigned short u[8]; } fu;
                #pragma unroll
                for (int j = 0; j < 8; ++j) {
                    float vv = xgp[(32 * cs + 8 * q + j) * HW];
                    ss[pt] = fmaf(vv, vv, ss[pt]);
                    fu.u[j] = f2bf(vv);
                }
                xf[pt][cs] = fu.v;
            }
        }
        #pragma unroll
        for (int pt = 0; pt < 4; ++pt) {
            float s = ss[pt];
            s += __shfl_xor(s, 16);
            s += __shfl_xor(s, 32);
            r2v[pt] = -2.0f / fmaxf(sqrtf(s), 1e-12f);  // F.normalize eps
        }
    }

    const float FMAX = __uint_as_float(0x7F7FFFFFu);
    float m1[4] = {FMAX, FMAX, FMAX, FMAX};
    float m2[4] = {FMAX, FMAX, FMAX, FMAX};
    float m3[4] = {FMAX, FMAX, FMAX, FMAX};

    // ---- main loop: 16 chunks of 16 codes, barrier-free ----
    const uint4* ap = (const uint4*)cbbf + (w * 16) * 256 + ln;
    #pragma unroll 4
    for (int i = 0; i < 16; ++i) {
        uint4 g0 = ap[0], g1 = ap[64], g2 = ap[128], g3 = ap[192];  // coalesced
        ap += 256;
        union { uint4 u; short8 s; } c0, c1, c2u, c3;
        c0.u = g0; c1.u = g1; c2u.u = g2; c3.u = g3;
        short8 ah[4] = {c0.s, c1.s, c2u.s, c3.s};

        f32x4 acc[4];
        #pragma unroll
        for (int pt = 0; pt < 4; ++pt) acc[pt] = 0;
        #pragma unroll
        for (int cs = 0; cs < 4; ++cs)
            #pragma unroll
            for (int pt = 0; pt < 4; ++pt)
                acc[pt] = __builtin_amdgcn_mfma_f32_16x16x32_bf16(
                    ah[cs], xf[pt][cs], acc[pt], 0, 0, 0);

        const int T16 = (w * 16 + i) * 16;              // chunk code base
        float4 c2vv = *(const float4*)(c2w + T16 + 4 * q);
        float c2a[4] = {c2vv.x, c2vv.y, c2vv.z, c2vv.w};
        const int kb0 = T16 + 4 * q;
        #pragma unroll
        for (int pt = 0; pt < 4; ++pt) {
            #pragma unroll
            for (int reg = 0; reg < 4; ++reg) {
                float s = fmaf(r2v[pt], acc[pt][reg], c2a[reg]);
                unsigned pb = (__float_as_uint(s) & 0xFFFFFC00u) |
                              (unsigned)(kb0 + reg);
                float u  = __uint_as_float(pb);
                float t3 = __builtin_amdgcn_fmed3f(m2[pt], m3[pt], u);
                float t2 = __builtin_amdgcn_fmed3f(m1[pt], m2[pt], u);
                m1[pt] = fminf(m1[pt], u); m2[pt] = t2; m3[pt] = t3;
            }
        }
    }

    // ---- butterfly across quad-lanes, publish per-wave chains ----
    #pragma unroll
    for (int d = 16; d <= 32; d <<= 1) {
        #pragma unroll
        for (int pt = 0; pt < 4; ++pt) {
            float o1 = __shfl_xor(m1[pt], d), o2 = __shfl_xor(m2[pt], d),
                  o3 = __shfl_xor(m3[pt], d);
            float u, t2, t3;
            u = o1; t3 = __builtin_amdgcn_fmed3f(m2[pt], m3[pt], u);
            t2 = __builtin_amdgcn_fmed3f(m1[pt], m2[pt], u);
            m1[pt] = fminf(m1[pt], u); m2[pt] = t2; m3[pt] = t3;
            u = o2; t3 = __builtin_amdgcn_fmed3f(m2[pt], m3[pt], u);
            t2 = __builtin_amdgcn_fmed3f(m1[pt], m2[pt], u);
            m1[pt] = fminf(m1[pt], u); m2[pt] = t2; m3[pt] = t3;
            u = o3; t3 = __builtin_amdgcn_fmed3f(m2[pt], m3[pt], u);
            t2 = __builtin_amdgcn_fmed3f(m1[pt], m2[pt], u);
            m1[pt] = fminf(m1[pt], u); m2[pt] = t2; m3[pt] = t3;
        }
    }
    if (ln < 16) {
        #pragma unroll
        for (int pt = 0; pt < 4; ++pt) {
            mbuf[w][pt][lp][0] = m1[pt];
            mbuf[w][pt][lp][1] = m2[pt];
            mbuf[w][pt][lp][2] = m3[pt];
        }
    }
    __syncthreads();                             // the ONLY block barrier

    // ---- wave w: merge 12 candidates + exact rescore for pos [16w,16w+16) --
    {
        float n1 = FMAX, n2 = FMAX, n3 = FMAX;
        #pragma unroll
        for (int wp = 0; wp < 4; ++wp) {
            #pragma unroll
            for (int c = 0; c < 3; ++c) {
                float u  = mbuf[wp][w][lp][c];   // broadcast over q-lanes
                float t3 = __builtin_amdgcn_fmed3f(n2, n3, u);
                float t2 = __builtin_amdgcn_fmed3f(n1, n2, u);
                n1 = fminf(n1, u); n2 = t2; n3 = t3;
            }
        }
        int ks[3] = {(int)(__float_as_uint(n1) & 1023u),
                     (int)(__float_as_uint(n2) & 1023u),
                     (int)(__float_as_uint(n3) & 1023u)};
        const float r2p = r2v[w];                // wave w's pt=w tile == its pos

        // re-read this position's 32 channels (L1/L2-hot)
        float xr[32];
        const float* xgp = x + b * CHW + s0 + 16 * w + lp;
        #pragma unroll
        for (int cs = 0; cs < 4; ++cs)
            #pragma unroll
            for (int j = 0; j < 8; ++j)
                xr[cs * 8 + j] = xgp[(32 * cs + 8 * q + j) * HW];

        // exact fp32 rescore (same fmaf order as R4-R9, all passed)
        float dots[3];
        #pragma unroll
        for (int jj = 0; jj < 3; ++jj) {
            const float* crow = cb + ks[jj] * C_DIM + 8 * q;
            float p = 0.f;
            #pragma unroll
            for (int cs = 0; cs < 4; ++cs) {
                float4 a0 = *(const float4*)(crow + 32 * cs);
                float4 a1 = *(const float4*)(crow + 32 * cs + 4);
                p = fmaf(xr[cs*8+0], a0.x, p); p = fmaf(xr[cs*8+1], a0.y, p);
                p = fmaf(xr[cs*8+2], a0.z, p); p = fmaf(xr[cs*8+3], a0.w, p);
                p = fmaf(xr[cs*8+4], a1.x, p); p = fmaf(xr[cs*8+5], a1.y, p);
                p = fmaf(xr[cs*8+6], a1.z, p); p = fmaf(xr[cs*8+7], a1.w, p);
            }
            p += __shfl_xor(p, 16);
            p += __shfl_xor(p, 32);
            dots[jj] = p;
        }
        float sb = fmaf(r2p, dots[0], c2w[ks[0]]); int kb = ks[0];
        float s2 = fmaf(r2p, dots[1], c2w[ks[1]]);
        if (s2 < sb || (s2 == sb && ks[1] < kb)) { sb = s2; kb = ks[1]; }
        float s3 = fmaf(r2p, dots[2], c2w[ks[2]]);
        if (s3 < sb || (s3 == sb && ks[2] < kb)) { sb = s3; kb = ks[2]; }

        if (ln < 16) idxw[bid * 64 + 16 * w + lp] = kb;

        float lv = (ln < 16) ? sqrtf(fmaxf(1.0f + sb, 0.f)) : 0.f;
        #pragma unroll
        for (int off = 32; off > 0; off >>= 1) lv += __shfl_down(lv, off);
        if (ln == 0) atomicAdd(Sw, lv);          // each position counted once
    }
}

// ---------------------------------------------------------------------------
// Kernel 3: scatter q = codebook[idx] + finalize losses (R7-proven v2).
// Thread = (position, channel-quad): one 16B row gather + 4 coalesced stores.
// ---------------------------------------------------------------------------
__global__ void write_q(const float* __restrict__ cb,
                        const int* __restrict__ idxw,
                        const float* __restrict__ ws,
                        float* __restrict__ out) {
    int id = blockIdx.x * 256 + threadIdx.x;   // 2,097,152 = N_POS * 32
    int p  = id & (N_POS - 1);                 // position (lanes consecutive)
    int c4 = id >> 16;                         // channel quad 0..31
    int b  = p >> 12, s = p & 4095;
    int row = idxw[p];                         // coalesced 4B reads
    float4 v = ((const float4*)cb)[row * 32 + c4];   // 16B gather, L2-hot
    float* o = out + b * CHW + (c4 * 4) * HW + s;
    o[0]      = v.x;                           // each store: 64 lanes x 4B
    o[HW]     = v.y;                           //  = coalesced 256B segment
    o[2 * HW] = v.z;
    o[3 * HW] = v.w;
    if (id == 0) {                             // fold in loss finalize
        float S = *(const float*)((const char*)ws + WS_S);
        float m = S / (float)N_POS;
        out[Q_ELEMS]     = 0.25f * m;
        out[Q_ELEMS + 1] = m;
    }
}

extern "C" void kernel_launch(void* const* d_in, const int* in_sizes, int n_in,
                              void* d_out, int out_size, void* d_ws, size_t ws_size,
                              hipStream_t stream) {
    const float* x  = (const float*)d_in[0];   // [16,128,64,64]
    const float* cb = (const float*)d_in[1];   // [1024,128]
    float* out = (float*)d_out;
    float* ws  = (float*)d_ws;

    int*  idxw = (int*)((char*)d_ws + WS_IDX);
    float* Sw  = (float*)((char*)d_ws + WS_S);
    unsigned short* cbbf = (unsigned short*)d_out;   // scratch in d_out (R7-proven)

    prep_kernel<<<K_CODES, 64, 0, stream>>>(cb, ws, cbbf);
    vq_mfma    <<<N_POS / 64, 256, 0, stream>>>(x, cb, cbbf, ws, idxw, Sw);
    write_q    <<<Q_ELEMS / 1024, 256, 0, stream>>>(cb, idxw, ws, out);
}

// Round 11
// 139.933 us; speedup vs baseline: 1.2969x; 1.1253x over previous
//
#include <hip/hip_runtime.h>
#include <math.h>

// Problem constants
#define K_CODES 1024
#define C_DIM   128
#define HW      4096          // 64*64
#define CHW     (C_DIM*HW)    // per-batch stride in x
#define N_POS   65536         // 16*64*64
#define Q_ELEMS 8388608       // 16*128*64*64

// ws layout (byte offsets). Total < 272 KB (proven safe rounds 1-10).
#define WS_S    0             // float: sum of sqrt(d2min)
#define WS_C2   256           // float[1024]: ||c_k||^2
#define WS_IDX  8192          // int[65536]: final argmin index per position

// d_out scratch (overwritten by write_q later; stream-ordered, proven R7):
//   offset 0: bf16 codebook, row k at k*256B, granule-col j holds channels of
//   granule (j ^ (k&7))  -> linear global_load_lds staging + conflict-free
//   swizzled ds_read_b128 A-frags.

typedef __attribute__((ext_vector_type(8))) short short8;   // 8 bf16 (4 VGPRs)
typedef __attribute__((ext_vector_type(4))) float f32x4;    // MFMA acc

__device__ __forceinline__ unsigned short f2bf(float f) {   // fp32 -> bf16 RNE
    unsigned u = __float_as_uint(f);
    u += 0x7FFFu + ((u >> 16) & 1u);
    return (unsigned short)(u >> 16);
}

// async global->LDS, 16B per lane; LDS dst = wave-uniform base + lane*16
__device__ __forceinline__ void gll16(const void* g, void* l) {
    __builtin_amdgcn_global_load_lds(
        (const __attribute__((address_space(1))) void*)g,
        (__attribute__((address_space(3))) void*)l, 16, 0, 0);
}

// ---------------------------------------------------------------------------
// Kernel 1: prep (byte-identical to R7). Block k (64 lanes): row norm, bf16
// conversion into the column-swizzled layout in d_out, S zeroing.
// ---------------------------------------------------------------------------
__global__ void prep_kernel(const float* __restrict__ cb, float* __restrict__ ws,
                            unsigned short* __restrict__ cbbf) {
    __shared__ __align__(16) unsigned short srow[128];
    int k = blockIdx.x;
    int l = threadIdx.x;                       // 64 lanes = 1 wave
    if (k == 0 && l == 0) *(float*)((char*)ws + WS_S) = 0.f;
    float v1 = cb[k * C_DIM + l];
    float v2 = cb[k * C_DIM + 64 + l];
    int c1 = l, c2 = 64 + l;
    srow[(((c1 >> 3) ^ (k & 7)) << 3) | (c1 & 7)] = f2bf(v1);
    srow[(((c2 >> 3) ^ (k & 7)) << 3) | (c2 & 7)] = f2bf(v2);
    float ss = v1 * v1 + v2 * v2;
    #pragma unroll
    for (int off = 32; off > 0; off >>= 1) ss += __shfl_down(ss, off);
    if (l == 0) ((float*)((char*)ws + WS_C2))[k] = ss;
    __syncthreads();
    if (l < 16) ((uint4*)cbbf)[k * 16 + l] = ((const uint4*)srow)[l];
}

// ---------------------------------------------------------------------------
// Kernel 2: fused VQ -- byte-identical to R7 (62 us, absmax 0.0).
// 1024 blocks x 256 thr. Block = 64 positions x all codes. Wave (pg,kh):
// pg = 32-position group, kh = 512-code half. __launch_bounds__(256,2).
// Per kh: 8 chunks of 64 codes, single-buffered 16 KB LDS via global_load_lds,
// pre-swizzled layout -> conflict-free ds_read_b128. Top-3 via min+2x med3
// with idx in low 10 mantissa bits; kh=1 publishes chains via LDS; kh=0
// merges + exact fp32 rescore + idx + loss.
// ---------------------------------------------------------------------------
__global__ __launch_bounds__(256, 2) void vq_mfma(const float* __restrict__ x,
                                                  const float* __restrict__ cb,
                                                  const unsigned short* __restrict__ cbbf,
                                                  const float* __restrict__ c2w,
                                                  int* __restrict__ idxw,
                                                  float* __restrict__ Sw) {
    __shared__ __align__(16) unsigned short cbuf[2 * 1024 * 8];  // 32 KB
    __shared__ float mbuf[2][2][16][3];                          // 768 B

    const int t  = threadIdx.x;
    const int w  = t >> 6;                      // wave 0..3
    const int kh = w & 1;                       // code half
    const int pg = w >> 1;                      // position group (32 pos)
    const int ln = t & 63;
    const int lp = ln & 15;                     // position lane (n index)
    const int q  = ln >> 4;                     // quad 0..3 (k sub-range)
    const int bid = blockIdx.x;
    const int b   = bid >> 6;                   // batch (64 blocks per image)
    const int s0  = (bid & 63) << 6;            // 64-position tile start

    // ---- x: bf16 B-frags (2 pos-tiles) + per-position norms ----
    short8 xf[2][4];
    float  r2v[2];
    {
        float ss[2] = {0.f, 0.f};
        #pragma unroll
        for (int pt = 0; pt < 2; ++pt) {
            const float* xgp = x + b * CHW + s0 + pg * 32 + pt * 16 + lp;
            #pragma unroll
            for (int cs = 0; cs < 4; ++cs) {
                union { short8 v; unsigned short u[8]; } fu;
                #pragma unroll
                for (int j = 0; j < 8; ++j) {
                    float vv = xgp[(32 * cs + 8 * q + j) * HW];
                    ss[pt] = fmaf(vv, vv, ss[pt]);
                    fu.u[j] = f2bf(vv);
                }
                xf[pt][cs] = fu.v;
            }
        }
        #pragma unroll
        for (int pt = 0; pt < 2; ++pt) {
            float s = ss[pt];
            s += __shfl_xor(s, 16);
            s += __shfl_xor(s, 32);
            r2v[pt] = -2.0f / fmaxf(sqrtf(s), 1e-12f);  // F.normalize eps
        }
    }

    const float FMAX = __uint_as_float(0x7F7FFFFFu);
    float m1[2] = {FMAX, FMAX}, m2[2] = {FMAX, FMAX}, m3[2] = {FMAX, FMAX};

    // staging bases: per-lane global addr, wave-uniform LDS base
    const char* gbase = (const char*)cbbf + (kh * 512) * 256 + (pg * 512 + ln) * 16;
    char* lbase = (char*)cbuf + (kh * 1024 + pg * 512) * 16;

    #pragma unroll
    for (int r = 0; r < 8; ++r)                  // stage chunk 0
        gll16(gbase + r * 1024, lbase + r * 1024);
    __syncthreads();

    for (int i = 0; i < 8; ++i) {
        const int k0 = kh * 512 + i * 64;

        f32x4 acc[4][2];
        #pragma unroll
        for (int ct = 0; ct < 4; ++ct)
            #pragma unroll
            for (int pt = 0; pt < 2; ++pt) acc[ct][pt] = 0;

        const unsigned short* cbp = cbuf + kh * 8192;
        #pragma unroll
        for (int cs = 0; cs < 4; ++cs) {
            short8 ah[4];
            #pragma unroll
            for (int ct = 0; ct < 4; ++ct) {     // A[m=16ct+lp][k=32cs+8q+j]
                int g = (16 * ct + lp) * 16 + ((4 * cs + q) ^ (lp & 7));
                ah[ct] = *(const short8*)(cbp + g * 8);
            }
            #pragma unroll
            for (int ct = 0; ct < 4; ++ct)
                #pragma unroll
                for (int pt = 0; pt < 2; ++pt)
                    acc[ct][pt] = __builtin_amdgcn_mfma_f32_16x16x32_bf16(
                        ah[ct], xf[pt][cs], acc[ct][pt], 0, 0, 0);
        }

        // ---- epilogue: 32 scores, ~5 VALU each (fmaf, and_or, 2 med3, min) --
        #pragma unroll
        for (int ct = 0; ct < 4; ++ct) {
            float4 c2vv = *(const float4*)(c2w + k0 + 16 * ct + 4 * q);
            float c2a[4] = {c2vv.x, c2vv.y, c2vv.z, c2vv.w};
            const int kb0 = k0 + 16 * ct + 4 * q;
            #pragma unroll
            for (int pt = 0; pt < 2; ++pt) {
                #pragma unroll
                for (int reg = 0; reg < 4; ++reg) {
                    float s = fmaf(r2v[pt], acc[ct][pt][reg], c2a[reg]);
                    unsigned pb = (__float_as_uint(s) & 0xFFFFFC00u) |
                                  (unsigned)(kb0 + reg);
                    float u  = __uint_as_float(pb);
                    float t3 = __builtin_amdgcn_fmed3f(m2[pt], m3[pt], u);
                    float t2 = __builtin_amdgcn_fmed3f(m1[pt], m2[pt], u);
                    m1[pt] = fminf(m1[pt], u); m2[pt] = t2; m3[pt] = t3;
                }
            }
        }

        if (i < 7) {
            __syncthreads();                     // all reads of buffer done
            #pragma unroll
            for (int r = 0; r < 8; ++r)
                gll16(gbase + (i + 1) * 16384 + r * 1024, lbase + r * 1024);
            __syncthreads();                     // loads landed (vmcnt drain)
        }
    }

    // ---- merge chains across the 4 quad-lanes (butterfly: all lanes get it) --
    #pragma unroll
    for (int d = 16; d <= 32; d <<= 1) {
        #pragma unroll
        for (int pt = 0; pt < 2; ++pt) {
            float o1 = __shfl_xor(m1[pt], d), o2 = __shfl_xor(m2[pt], d),
                  o3 = __shfl_xor(m3[pt], d);
            float u, t2, t3;
            u = o1; t3 = __builtin_amdgcn_fmed3f(m2[pt], m3[pt], u);
            t2 = __builtin_amdgcn_fmed3f(m1[pt], m2[pt], u);
            m1[pt] = fminf(m1[pt], u); m2[pt] = t2; m3[pt] = t3;
            u = o2; t3 = __builtin_amdgcn_fmed3f(m2[pt], m3[pt], u);
            t2 = __builtin_amdgcn_fmed3f(m1[pt], m2[pt], u);
            m1[pt] = fminf(m1[pt], u); m2[pt] = t2; m3[pt] = t3;
            u = o3; t3 = __builtin_amdgcn_fmed3f(m2[pt], m3[pt], u);
            t2 = __builtin_amdgcn_fmed3f(m1[pt], m2[pt], u);
            m1[pt] = fminf(m1[pt], u); m2[pt] = t2; m3[pt] = t3;
        }
    }

    if (kh == 1 && ln < 16) {
        #pragma unroll
        for (int pt = 0; pt < 2; ++pt) {
            mbuf[pg][pt][lp][0] = m1[pt];
            mbuf[pg][pt][lp][1] = m2[pt];
            mbuf[pg][pt][lp][2] = m3[pt];
        }
    }
    __syncthreads();

    if (kh == 0) {
        float lsum = 0.f;
        #pragma unroll
        for (int pt = 0; pt < 2; ++pt) {
            // merge the kh=1 half's chain (broadcast LDS reads)
            #pragma unroll
            for (int c = 0; c < 3; ++c) {
                float u  = mbuf[pg][pt][lp][c];
                float t3 = __builtin_amdgcn_fmed3f(m2[pt], m3[pt], u);
                float t2 = __builtin_amdgcn_fmed3f(m1[pt], m2[pt], u);
                m1[pt] = fminf(m1[pt], u); m2[pt] = t2; m3[pt] = t3;
            }
            int ks[3] = {(int)(__float_as_uint(m1[pt]) & 1023u),
                         (int)(__float_as_uint(m2[pt]) & 1023u),
                         (int)(__float_as_uint(m3[pt]) & 1023u)};

            // re-read this position's 32 channels (L1/L2-hot)
            float xr[32];
            const float* xgp = x + b * CHW + s0 + pg * 32 + pt * 16 + lp;
            #pragma unroll
            for (int cs = 0; cs < 4; ++cs)
                #pragma unroll
                for (int j = 0; j < 8; ++j)
                    xr[cs * 8 + j] = xgp[(32 * cs + 8 * q + j) * HW];

            // exact fp32 rescore of the 3 candidates (same order as R4-R10)
            float dots[3];
            #pragma unroll
            for (int jj = 0; jj < 3; ++jj) {
                const float* crow = cb + ks[jj] * C_DIM + 8 * q;
                float p = 0.f;
                #pragma unroll
                for (int cs = 0; cs < 4; ++cs) {
                    float4 a0 = *(const float4*)(crow + 32 * cs);
                    float4 a1 = *(const float4*)(crow + 32 * cs + 4);
                    p = fmaf(xr[cs*8+0], a0.x, p); p = fmaf(xr[cs*8+1], a0.y, p);
                    p = fmaf(xr[cs*8+2], a0.z, p); p = fmaf(xr[cs*8+3], a0.w, p);
                    p = fmaf(xr[cs*8+4], a1.x, p); p = fmaf(xr[cs*8+5], a1.y, p);
                    p = fmaf(xr[cs*8+6], a1.z, p); p = fmaf(xr[cs*8+7], a1.w, p);
                }
                p += __shfl_xor(p, 16);
                p += __shfl_xor(p, 32);
                dots[jj] = p;
            }
            float sb = fmaf(r2v[pt], dots[0], c2w[ks[0]]); int kb = ks[0];
            float s2 = fmaf(r2v[pt], dots[1], c2w[ks[1]]);
            if (s2 < sb || (s2 == sb && ks[1] < kb)) { sb = s2; kb = ks[1]; }
            float s3 = fmaf(r2v[pt], dots[2], c2w[ks[2]]);
            if (s3 < sb || (s3 == sb && ks[2] < kb)) { sb = s3; kb = ks[2]; }

            if (ln < 16) idxw[bid * 64 + pg * 32 + pt * 16 + lp] = kb;
            lsum += sqrtf(fmaxf(1.0f + sb, 0.f));   // z2 == 1 after normalize
        }
        // each position counted by its 4 q-lanes -> scale 0.25
        #pragma unroll
        for (int off = 32; off > 0; off >>= 1) lsum += __shfl_down(lsum, off);
        if (ln == 0) atomicAdd(Sw, 0.25f * lsum);
    }
}

// ---------------------------------------------------------------------------
// Kernel 3: write_q v3 -- WAVE-COOPERATIVE scatter (zero gather fan-out).
// Block = 64 positions (matches idxw layout). Phase A: rows gathered with
// wave-uniform row index -> every cb read is a coalesced 256B segment, into
// stride-129 LDS (banks (p+ln)%32: 2-way = free). Phase B: lane = position,
// 32 coalesced 256B stores per wave (banks (ln+c)%32: 2-way = free).
// Loss finalize folded into block 0 (Sw final by stream order).
// Prior write_q v2's per-lane random-row float4 gathers fanned out ~64 L1
// transactions per wave-instruction -- suspected ~40 us, never profiled.
// ---------------------------------------------------------------------------
__global__ void write_q(const float* __restrict__ cb,
                        const int* __restrict__ idxw,
                        const float* __restrict__ ws,
                        float* __restrict__ out) {
    __shared__ int   ki[64];
    __shared__ float qT[64 * 129];             // 33024 B, pad-129 LDS
    const int t  = threadIdx.x;
    const int w  = t >> 6;                     // wave 0..3
    const int ln = t & 63;
    const int bid = blockIdx.x;
    const int b   = bid >> 6;
    const int s0  = (bid & 63) << 6;

    if (t < 64) ki[t] = idxw[bid * 64 + t];
    __syncthreads();

    // Phase A: wave w gathers rows for positions [16w, 16w+16)
    #pragma unroll 4
    for (int i = 0; i < 16; ++i) {
        const int p   = 16 * w + i;
        const int row = ki[p];                 // wave-uniform -> coalesced read
        qT[p * 129 + ln]      = cb[row * C_DIM + ln];
        qT[p * 129 + 64 + ln] = cb[row * C_DIM + 64 + ln];
    }
    __syncthreads();

    // Phase B: lane = position; wave w writes channels [32w, 32w+32)
    float* o = out + b * CHW + s0 + ln;
    #pragma unroll 8
    for (int cc = 0; cc < 32; ++cc) {
        const int c = 32 * w + cc;
        o[c * HW] = qT[ln * 129 + c];          // 64 lanes x 4B = 256B coalesced
    }

    if (bid == 0 && t == 0) {                  // loss finalize
        float S = *(const float*)((const char*)ws + WS_S);
        float m = S / (float)N_POS;
        out[Q_ELEMS]     = 0.25f * m;
        out[Q_ELEMS + 1] = m;
    }
}

extern "C" void kernel_launch(void* const* d_in, const int* in_sizes, int n_in,
                              void* d_out, int out_size, void* d_ws, size_t ws_size,
                              hipStream_t stream) {
    const float* x  = (const float*)d_in[0];   // [16,128,64,64]
    const float* cb = (const float*)d_in[1];   // [1024,128]
    float* out = (float*)d_out;
    float* ws  = (float*)d_ws;

    const float* c2w = (const float*)((const char*)d_ws + WS_C2);
    int*  idxw = (int*)((char*)d_ws + WS_IDX);
    float* Sw  = (float*)((char*)d_ws + WS_S);
    unsigned short* cbbf = (unsigned short*)d_out;   // scratch in d_out (R7-proven)

    prep_kernel<<<K_CODES, 64, 0, stream>>>(cb, ws, cbbf);
    vq_mfma    <<<N_POS / 64, 256, 0, stream>>>(x, cb, cbbf, c2w, idxw, Sw);
    write_q    <<<N_POS / 64, 256, 0, stream>>>(cb, idxw, ws, out);
}